// Round 10
// baseline (219.587 us; speedup 1.0000x reference)
//
#include <hip/hip_runtime.h>
#include <hip/hip_bf16.h>
#include <hip/hip_fp16.h>

// ---------------------------------------------------------------------------
// GCN 3-layer forward.
//  - All 3 GEMMs: bf16 MFMA (16x16x32), fp32 accum, bf16 output (the output
//    is gathered as bf16 anyway, so MFMA input quant adds ~nothing).
//  - Aggregation: CSR-by-dst gather of bf16 rows, fp32 accum, 2 nodes/wave,
//    SOFTWARE-PIPELINED: rows double-buffered (rP/rQ) + 3 rotating meta
//    buffers -> next iteration's 16 gathers are in flight while this
//    iteration's FMAs run (32 gathers outstanding, half the exposed latency).
//  - CSR build via RANK-FROM-HIST: k_hist's atomicAdd return value is the
//    edge's slot rank -> k_fill is atomic-free.
//  - Edge record: u32 {fp16 norm | u16 src}. Rows padded to x8, pad = 0.
//    Self-loop occupies reserved rank 0 (deg initialized to 1).
// ---------------------------------------------------------------------------

typedef __attribute__((ext_vector_type(8))) short s16x8;
typedef __attribute__((ext_vector_type(8))) unsigned short u16x8;
typedef __attribute__((ext_vector_type(4))) float f32x4;

__device__ __forceinline__ float bfu_lo(uint v) { return __uint_as_float(v << 16); }
__device__ __forceinline__ float bfu_hi(uint v) { return __uint_as_float(v & 0xffff0000u); }
__device__ __forceinline__ float dec_norm(uint m) {
    return __half2float(__ushort_as_half((ushort)(m >> 16)));
}
__device__ __forceinline__ ushort bf16_bits(float f) {
    union { __hip_bfloat16 h; ushort u; } x;
    x.h = __float2bfloat16(f);
    return x.u;
}

// ---------------- CSR build ----------------

__global__ void k_init(int* __restrict__ deg, int n,
                       uint4* __restrict__ ep4, int cap4) {
    int i = blockIdx.x * blockDim.x + threadIdx.x;
    if (i < n) deg[i] = 1;                       // slot 0 reserved: self-loop
    if (i < cap4) ep4[i] = make_uint4(0u, 0u, 0u, 0u);
}

__global__ void k_hist(const int* __restrict__ dst, int E,
                       int* __restrict__ deg, ushort* __restrict__ rank) {
    int e = blockIdx.x * blockDim.x + threadIdx.x;
    if (e < E) {
        int r = atomicAdd(&deg[dst[e]], 1);
        rank[e] = (ushort)r;
    }
}

__global__ void k_scan_block(const int* __restrict__ deg, int* __restrict__ offs,
                             int* __restrict__ bsum, float* __restrict__ dinv, int n) {
    __shared__ int sm[256];
    int tid = threadIdx.x;
    int i = blockIdx.x * 256 + tid;
    int v = (i < n) ? deg[i] : 0;
    int pv = (i < n) ? ((v + 7) & ~7) : 0;   // pad rows to x8
    if (i < n) dinv[i] = rsqrtf((float)v);
    sm[tid] = pv;
    __syncthreads();
    for (int off = 1; off < 256; off <<= 1) {
        int t = (tid >= off) ? sm[tid - off] : 0;
        __syncthreads();
        sm[tid] += t;
        __syncthreads();
    }
    if (i < n) offs[i] = sm[tid] - pv;
    if (tid == 255) bsum[blockIdx.x] = sm[255];
}

__global__ void k_scan_bsum(int* __restrict__ bsum, int nb, int* __restrict__ offs, int n) {
    __shared__ int sm[256];
    int tid = threadIdx.x;
    int v = (tid < nb) ? bsum[tid] : 0;
    sm[tid] = v;
    __syncthreads();
    for (int off = 1; off < 256; off <<= 1) {
        int t = (tid >= off) ? sm[tid - off] : 0;
        __syncthreads();
        sm[tid] += t;
        __syncthreads();
    }
    if (tid < nb) bsum[tid] = sm[tid] - v;
    if (tid == 255) offs[n] = sm[255];
}

__global__ void k_add_bsum(int* __restrict__ offs, const int* __restrict__ bsum, int n) {
    int i = blockIdx.x * blockDim.x + threadIdx.x;
    if (i < n) offs[i] += bsum[i >> 8];
}

__global__ __launch_bounds__(256) void k_fill(const int* __restrict__ src,
                                              const int* __restrict__ dst,
                                              const ushort* __restrict__ rank,
                                              int E, int n,
                                              const int* __restrict__ offs,
                                              const float* __restrict__ dinv,
                                              uint* __restrict__ ep) {
    int e = blockIdx.x * blockDim.x + threadIdx.x;
    int tot = E + n;
    if (e >= tot) return;
    int s, d, r;
    if (e < E) {
        s = src[e];
        d = dst[e];
        r = rank[e];
    } else {
        s = d = e - E;
        r = 0;
    }
    int pos = offs[d] + r;
    uint hb = (uint)__half_as_ushort(__float2half(dinv[s] * dinv[d]));
    ep[pos] = (hb << 16) | (uint)s;
}

// ---------------- W transpose+quantize (once per launch) ----------------
__global__ void k_transW(const float* __restrict__ W1, const float* __restrict__ W2,
                         const float* __restrict__ W3,
                         ushort* __restrict__ Wt1, ushort* __restrict__ Wt2,
                         ushort* __restrict__ Wt3) {
    int i = blockIdx.x * 256 + threadIdx.x;
    if (i < 128 * 128) {
        int r = i >> 7, c = i & 127;
        Wt1[c * 128 + r] = bf16_bits(W1[i]);
        Wt2[c * 128 + r] = bf16_bits(W2[i]);
    }
    if (i < 128 * 64) {
        int r = i >> 6, c = i & 63;
        Wt3[c * 128 + r] = bf16_bits(W3[i]);
    }
}

// ---------------- MFMA GEMM: T = A @ W, bf16 in, bf16 out ----------------
// BM=64, 256 threads = 4 waves; wave w owns rows w*16..w*16+15, all OUT cols.
template <int OUT, bool ABF16>
__global__ __launch_bounds__(256) void k_gemm_mfma(const void* __restrict__ Ain,
                                                   const ushort* __restrict__ Wt,
                                                   ushort* __restrict__ To, int n) {
    constexpr int NT = OUT / 16;
    __shared__ ushort As[64][136];
    __shared__ ushort Ws[OUT][136];
    const int tid = threadIdx.x;
    const int wave = tid >> 6, lane = tid & 63;
    const int m0 = blockIdx.x * 64;

#pragma unroll
    for (int it = 0; it < OUT / 16; ++it) {      // OUT*16 u16x8 chunks / 256
        int idx = it * 256 + tid;
        int r = idx >> 4;
        int c8 = (idx & 15) << 3;
        *(u16x8*)&Ws[r][c8] = *(const u16x8*)(Wt + r * 128 + c8);
    }
    if constexpr (ABF16) {
        const ushort* A = (const ushort*)Ain;
#pragma unroll
        for (int it = 0; it < 4; ++it) {
            int idx = it * 256 + tid;
            int r = idx >> 4;
            int c8 = (idx & 15) << 3;
            u16x8 v = {0, 0, 0, 0, 0, 0, 0, 0};
            if (m0 + r < n) v = *(const u16x8*)(A + (size_t)(m0 + r) * 128 + c8);
            *(u16x8*)&As[r][c8] = v;
        }
    } else {
        const float* A = (const float*)Ain;
#pragma unroll
        for (int it = 0; it < 8; ++it) {
            int idx = it * 256 + tid;
            int r = idx >> 5;
            int c4 = (idx & 31) << 2;
            float4 v = make_float4(0.f, 0.f, 0.f, 0.f);
            if (m0 + r < n) v = *(const float4*)(A + (size_t)(m0 + r) * 128 + c4);
            As[r][c4 + 0] = bf16_bits(v.x);
            As[r][c4 + 1] = bf16_bits(v.y);
            As[r][c4 + 2] = bf16_bits(v.z);
            As[r][c4 + 3] = bf16_bits(v.w);
        }
    }
    __syncthreads();

    const int lrow = lane & 15;
    const int kgrp = lane >> 4;

    s16x8 a[4];
#pragma unroll
    for (int kk = 0; kk < 4; ++kk)
        a[kk] = *(const s16x8*)&As[wave * 16 + lrow][kk * 32 + kgrp * 8];

    f32x4 acc[NT];
#pragma unroll
    for (int nt = 0; nt < NT; ++nt) {
        f32x4 c = {0.f, 0.f, 0.f, 0.f};
#pragma unroll
        for (int kk = 0; kk < 4; ++kk) {
            s16x8 b = *(const s16x8*)&Ws[nt * 16 + lrow][kk * 32 + kgrp * 8];
            c = __builtin_amdgcn_mfma_f32_16x16x32_bf16(a[kk], b, c, 0, 0, 0);
        }
        acc[nt] = c;
    }

#pragma unroll
    for (int j = 0; j < 4; ++j) {
        int row = m0 + wave * 16 + kgrp * 4 + j;
        if (row < n) {
#pragma unroll
            for (int nt = 0; nt < NT; ++nt)
                To[(size_t)row * OUT + nt * 16 + lrow] = bf16_bits(acc[nt][j]);
        }
    }
}

// ---------------- Aggregation helpers ----------------

__device__ __forceinline__ void fetch16(const uint* __restrict__ ep,
                                        int eA0, int itA, int eB0, int itB,
                                        int k, uint (&m)[16]) {
    if (k < itA) {
        uint4 a0 = *(const uint4*)(ep + eA0 + (k << 3));
        uint4 a1 = *(const uint4*)(ep + eA0 + (k << 3) + 4);
        m[0] = a0.x; m[1] = a0.y; m[2] = a0.z; m[3] = a0.w;
        m[4] = a1.x; m[5] = a1.y; m[6] = a1.z; m[7] = a1.w;
    } else {
#pragma unroll
        for (int i = 0; i < 8; ++i) m[i] = 0u;
    }
    if (k < itB) {
        uint4 b0 = *(const uint4*)(ep + eB0 + (k << 3));
        uint4 b1 = *(const uint4*)(ep + eB0 + (k << 3) + 4);
        m[8] = b0.x;  m[9] = b0.y;  m[10] = b0.z; m[11] = b0.w;
        m[12] = b1.x; m[13] = b1.y; m[14] = b1.z; m[15] = b1.w;
    } else {
#pragma unroll
        for (int i = 8; i < 16; ++i) m[i] = 0u;
    }
}

__device__ __forceinline__ void gather16u(const uint* __restrict__ Tl,
                                          const uint (&m)[16], uint (&r)[16]) {
#pragma unroll
    for (int i = 0; i < 16; ++i) r[i] = Tl[(size_t)(m[i] & 0xffffu) * 64];
}

__device__ __forceinline__ void fma16u(const uint (&m)[16], const uint (&r)[16],
                                       float& a0, float& a1, float& c0, float& c1) {
#pragma unroll
    for (int i = 0; i < 8; ++i) {
        float w = dec_norm(m[i]);
        a0 += w * bfu_lo(r[i]);
        a1 += w * bfu_hi(r[i]);
    }
#pragma unroll
    for (int i = 8; i < 16; ++i) {
        float w = dec_norm(m[i]);
        c0 += w * bfu_lo(r[i]);
        c1 += w * bfu_hi(r[i]);
    }
}

__device__ __forceinline__ void gather16s(const ushort* __restrict__ Tl,
                                          const uint (&m)[16], uint (&r)[16]) {
#pragma unroll
    for (int i = 0; i < 16; ++i) r[i] = (uint)Tl[(size_t)(m[i] & 0xffffu) * 64];
}

__device__ __forceinline__ void fma16s(const uint (&m)[16], const uint (&r)[16],
                                       float& a0, float& c0) {
#pragma unroll
    for (int i = 0; i < 8; ++i)
        a0 += dec_norm(m[i]) * __uint_as_float(r[i] << 16);
#pragma unroll
    for (int i = 8; i < 16; ++i)
        c0 += dec_norm(m[i]) * __uint_as_float(r[i] << 16);
}

// ---------------- Aggregation: 2 nodes/wave, pipelined double-buffer ------
// D=128: lane owns dims {2*lane, 2*lane+1}; one 4B gather covers the 256B
// row per wave. Output packed bf16x2.
#define AGG_HALF(GATHER, Mnext, Mfetch, Rnext, Mcur, Rcur, FMA) \
    GATHER(Tl, Mnext, Rnext);                                   \
    fetch16(ep, eA0, itA, eB0, itB, j + 2, Mfetch);             \
    FMA;                                                        \
    if (++j >= iters) break;

template <bool RELU>
__global__ __launch_bounds__(256) void k_agg128(const ushort* __restrict__ T,
                                                const int* __restrict__ offs,
                                                const uint* __restrict__ ep,
                                                const float* __restrict__ bias,
                                                uint* __restrict__ outq, int n) {
    int pr = blockIdx.x * 4 + (threadIdx.x >> 6);
    int lane = threadIdx.x & 63;
    int w0 = pr * 2;
    if (w0 >= n) return;
    int w1 = w0 + 1;
    bool has1 = (w1 < n);
    int eA0 = offs[w0];
    int itA = (offs[w0 + 1] - eA0) >> 3;
    int eB0 = has1 ? offs[w1] : 0;
    int itB = has1 ? ((offs[w1 + 1] - eB0) >> 3) : 0;
    int iters = max(itA, itB);

    const uint* Tl = (const uint*)T + lane;
    float a0 = 0.f, a1 = 0.f, c0 = 0.f, c1 = 0.f;
    uint M0[16], M1[16], M2[16], rP[16], rQ[16];

    fetch16(ep, eA0, itA, eB0, itB, 0, M0);
    gather16u(Tl, M0, rP);
    fetch16(ep, eA0, itA, eB0, itB, 1, M1);
    int j = 0;
    for (;;) {
        AGG_HALF(gather16u, M1, M2, rQ, M0, rP, fma16u(M0, rP, a0, a1, c0, c1))
        AGG_HALF(gather16u, M2, M0, rP, M1, rQ, fma16u(M1, rQ, a0, a1, c0, c1))
        AGG_HALF(gather16u, M0, M1, rQ, M2, rP, fma16u(M2, rP, a0, a1, c0, c1))
        AGG_HALF(gather16u, M1, M2, rP, M0, rQ, fma16u(M0, rQ, a0, a1, c0, c1))
        AGG_HALF(gather16u, M2, M0, rQ, M1, rP, fma16u(M1, rP, a0, a1, c0, c1))
        AGG_HALF(gather16u, M0, M1, rP, M2, rQ, fma16u(M2, rQ, a0, a1, c0, c1))
    }

    float2 b = *(const float2*)(bias + (lane << 1));
    a0 += b.x; a1 += b.y;
    if (RELU) { a0 = fmaxf(a0, 0.f); a1 = fmaxf(a1, 0.f); }
    outq[(size_t)w0 * 64 + lane] = ((uint)bf16_bits(a1) << 16) | (uint)bf16_bits(a0);
    if (has1) {
        c0 += b.x; c1 += b.y;
        if (RELU) { c0 = fmaxf(c0, 0.f); c1 = fmaxf(c1, 0.f); }
        outq[(size_t)w1 * 64 + lane] = ((uint)bf16_bits(c1) << 16) | (uint)bf16_bits(c0);
    }
}

// D=64 final layer: lane owns 1 dim, fp32 output.
__global__ __launch_bounds__(256) void k_agg64(const ushort* __restrict__ T,
                                               const int* __restrict__ offs,
                                               const uint* __restrict__ ep,
                                               const float* __restrict__ bias,
                                               float* __restrict__ out, int n) {
    int pr = blockIdx.x * 4 + (threadIdx.x >> 6);
    int lane = threadIdx.x & 63;
    int w0 = pr * 2;
    if (w0 >= n) return;
    int w1 = w0 + 1;
    bool has1 = (w1 < n);
    int eA0 = offs[w0];
    int itA = (offs[w0 + 1] - eA0) >> 3;
    int eB0 = has1 ? offs[w1] : 0;
    int itB = has1 ? ((offs[w1 + 1] - eB0) >> 3) : 0;
    int iters = max(itA, itB);

    const ushort* Tl = T + lane;
    float a0 = 0.f, c0 = 0.f;
    uint M0[16], M1[16], M2[16], rP[16], rQ[16];

    fetch16(ep, eA0, itA, eB0, itB, 0, M0);
    gather16s(Tl, M0, rP);
    fetch16(ep, eA0, itA, eB0, itB, 1, M1);
    int j = 0;
    for (;;) {
        AGG_HALF(gather16s, M1, M2, rQ, M0, rP, fma16s(M0, rP, a0, c0))
        AGG_HALF(gather16s, M2, M0, rP, M1, rQ, fma16s(M1, rQ, a0, c0))
        AGG_HALF(gather16s, M0, M1, rQ, M2, rP, fma16s(M2, rP, a0, c0))
        AGG_HALF(gather16s, M1, M2, rP, M0, rQ, fma16s(M0, rQ, a0, c0))
        AGG_HALF(gather16s, M2, M0, rQ, M1, rP, fma16s(M1, rP, a0, c0))
        AGG_HALF(gather16s, M0, M1, rP, M2, rQ, fma16s(M2, rQ, a0, c0))
    }

    float bv = bias[lane];
    out[(size_t)w0 * 64 + lane] = a0 + bv;
    if (has1) out[(size_t)w1 * 64 + lane] = c0 + bv;
}

// ---------------------------------------------------------------------------

extern "C" void kernel_launch(void* const* d_in, const int* in_sizes, int n_in,
                              void* d_out, int out_size, void* d_ws, size_t ws_size,
                              hipStream_t stream) {
    const int n = in_sizes[0] / 128;   // 50000
    const int E = in_sizes[1] / 2;     // 800000

    const float* x  = (const float*)d_in[0];
    const int*   ei = (const int*)d_in[1];
    const float* W1 = (const float*)d_in[2];
    const float* b1 = (const float*)d_in[3];
    const float* W2 = (const float*)d_in[4];
    const float* b2 = (const float*)d_in[5];
    const float* W3 = (const float*)d_in[6];
    const float* b3 = (const float*)d_in[7];
    const int* src = ei;
    const int* dst = ei + E;
    float* out = (float*)d_out;

    const int cap = E + 8 * n;  // max padded slots

    char* w = (char*)d_ws;
    auto alloc = [&](size_t bytes) {
        char* p = w;
        w += (bytes + 255) & ~(size_t)255;
        return p;
    };
    int*    deg    = (int*)alloc((size_t)n * 4);
    int*    offs   = (int*)alloc((size_t)(n + 1) * 4);
    int*    bsum   = (int*)alloc(256 * 4);
    float*  dinv   = (float*)alloc((size_t)n * 4);
    ushort* rank   = (ushort*)alloc((size_t)E * 2);
    uint*   ep     = (uint*)alloc((size_t)cap * 4);
    ushort* tA     = (ushort*)alloc((size_t)n * 128 * 2);  // gathered t (bf16)
    uint*   hB     = (uint*)alloc((size_t)n * 64 * 4);     // h packed bf16x2
    ushort* Wt1    = (ushort*)alloc(128 * 128 * 2);
    ushort* Wt2    = (ushort*)alloc(128 * 128 * 2);
    ushort* Wt3    = (ushort*)alloc(64 * 128 * 2);

    const int nb = (n + 255) / 256;

    // ---- CSR build + weight prep ----
    const int cap4 = (cap + 3) / 4;
    k_init<<<(cap4 + 255) / 256, 256, 0, stream>>>(deg, n, (uint4*)ep, cap4);
    k_transW<<<64, 256, 0, stream>>>(W1, W2, W3, Wt1, Wt2, Wt3);
    k_hist<<<(E + 255) / 256, 256, 0, stream>>>(dst, E, deg, rank);
    k_scan_block<<<nb, 256, 0, stream>>>(deg, offs, bsum, dinv, n);
    k_scan_bsum<<<1, 256, 0, stream>>>(bsum, nb, offs, n);
    k_add_bsum<<<nb, 256, 0, stream>>>(offs, bsum, n);
    k_fill<<<(E + n + 255) / 256, 256, 0, stream>>>(src, dst, rank, E, n, offs, dinv, ep);

    // ---- 3 GCN layers ----
    const int pair_blocks = ((n + 1) / 2 + 3) / 4;   // 2 nodes/wave, 4 waves/block
    const int gemm_blocks = (n + 63) / 64;

    k_gemm_mfma<128, false><<<gemm_blocks, 256, 0, stream>>>(x, Wt1, tA, n);
    k_agg128<true><<<pair_blocks, 256, 0, stream>>>(tA, offs, ep, b1, hB, n);

    k_gemm_mfma<128, true><<<gemm_blocks, 256, 0, stream>>>(hB, Wt2, tA, n);
    k_agg128<true><<<pair_blocks, 256, 0, stream>>>(tA, offs, ep, b2, hB, n);

    k_gemm_mfma<64, true><<<gemm_blocks, 256, 0, stream>>>(hB, Wt3, tA, n);
    k_agg64<<<pair_blocks, 256, 0, stream>>>(tA, offs, ep, b3, out, n);
}

// Round 12
// 187.583 us; speedup vs baseline: 1.1706x; 1.1706x over previous
//
#include <hip/hip_runtime.h>
#include <hip/hip_bf16.h>
#include <hip/hip_fp16.h>

// ---------------------------------------------------------------------------
// GCN 3-layer forward.
//  - All 3 GEMMs: bf16 MFMA (16x16x32), fp32 accum, bf16 output (the output
//    is gathered as bf16 anyway, so MFMA input quant adds ~nothing).
//  - Aggregation: CSR-by-dst gather of bf16 rows, fp32 accum, 2 nodes/wave,
//    16 gathers in flight, 1-deep metadata prefetch.
//  - CSR build via RANK-FROM-HIST: k_hist's atomicAdd return value is the
//    edge's slot rank -> k_fill is atomic-free.
//  - Edge record: u32 {fp16 norm | u16 src}. Rows padded to x8, pad = 0.
//    Self-loop occupies reserved rank 0 (deg initialized to 1).
//  Determinism audit (R11 failure follow-up): every ws buffer is fully
//  rewritten before first read within each launch; only in-row rank ORDER
//  varies across calls (ulp-level fp reassociation only).
// ---------------------------------------------------------------------------

typedef __attribute__((ext_vector_type(8))) short s16x8;
typedef __attribute__((ext_vector_type(8))) unsigned short u16x8;
typedef __attribute__((ext_vector_type(4))) float f32x4;

__device__ __forceinline__ float bfu_lo(uint v) { return __uint_as_float(v << 16); }
__device__ __forceinline__ float bfu_hi(uint v) { return __uint_as_float(v & 0xffff0000u); }
__device__ __forceinline__ float dec_norm(uint m) {
    return __half2float(__ushort_as_half((ushort)(m >> 16)));
}
__device__ __forceinline__ ushort bf16_bits(float f) {
    union { __hip_bfloat16 h; ushort u; } x;
    x.h = __float2bfloat16(f);
    return x.u;
}

// ---------------- CSR build ----------------

__global__ void k_init(int* __restrict__ deg, int n,
                       uint4* __restrict__ ep4, int cap4) {
    int i = blockIdx.x * blockDim.x + threadIdx.x;
    if (i < n) deg[i] = 1;                       // slot 0 reserved: self-loop
    if (i < cap4) ep4[i] = make_uint4(0u, 0u, 0u, 0u);
}

// histogram + per-edge rank (the atomic's return value IS the CSR slot index)
__global__ void k_hist(const int* __restrict__ dst, int E,
                       int* __restrict__ deg, ushort* __restrict__ rank) {
    int e = blockIdx.x * blockDim.x + threadIdx.x;
    if (e < E) {
        int r = atomicAdd(&deg[dst[e]], 1);
        rank[e] = (ushort)r;                     // deg <= ~60 << 65536
    }
}

__global__ void k_scan_block(const int* __restrict__ deg, int* __restrict__ offs,
                             int* __restrict__ bsum, float* __restrict__ dinv, int n) {
    __shared__ int sm[256];
    int tid = threadIdx.x;
    int i = blockIdx.x * 256 + tid;
    int v = (i < n) ? deg[i] : 0;
    int pv = (i < n) ? ((v + 7) & ~7) : 0;   // pad rows to x8
    if (i < n) dinv[i] = rsqrtf((float)v);
    sm[tid] = pv;
    __syncthreads();
    for (int off = 1; off < 256; off <<= 1) {
        int t = (tid >= off) ? sm[tid - off] : 0;
        __syncthreads();
        sm[tid] += t;
        __syncthreads();
    }
    if (i < n) offs[i] = sm[tid] - pv;
    if (tid == 255) bsum[blockIdx.x] = sm[255];
}

__global__ void k_scan_bsum(int* __restrict__ bsum, int nb, int* __restrict__ offs, int n) {
    __shared__ int sm[256];
    int tid = threadIdx.x;
    int v = (tid < nb) ? bsum[tid] : 0;
    sm[tid] = v;
    __syncthreads();
    for (int off = 1; off < 256; off <<= 1) {
        int t = (tid >= off) ? sm[tid - off] : 0;
        __syncthreads();
        sm[tid] += t;
        __syncthreads();
    }
    if (tid < nb) bsum[tid] = sm[tid] - v;
    if (tid == 255) offs[n] = sm[255];
}

__global__ void k_add_bsum(int* __restrict__ offs, const int* __restrict__ bsum, int n) {
    int i = blockIdx.x * blockDim.x + threadIdx.x;
    if (i < n) offs[i] += bsum[i >> 8];
}

// atomic-free CSR fill: pos = offs[dst] + rank (self-loop -> rank 0).
__global__ __launch_bounds__(256) void k_fill(const int* __restrict__ src,
                                              const int* __restrict__ dst,
                                              const ushort* __restrict__ rank,
                                              int E, int n,
                                              const int* __restrict__ offs,
                                              const float* __restrict__ dinv,
                                              uint* __restrict__ ep) {
    int e = blockIdx.x * blockDim.x + threadIdx.x;
    int tot = E + n;
    if (e >= tot) return;
    int s, d, r;
    if (e < E) {
        s = src[e];
        d = dst[e];
        r = rank[e];
    } else {
        s = d = e - E;
        r = 0;
    }
    int pos = offs[d] + r;
    uint hb = (uint)__half_as_ushort(__float2half(dinv[s] * dinv[d]));
    ep[pos] = (hb << 16) | (uint)s;
}

// ---------------- W transpose+quantize (once per launch) ----------------
__global__ void k_transW(const float* __restrict__ W1, const float* __restrict__ W2,
                         const float* __restrict__ W3,
                         ushort* __restrict__ Wt1, ushort* __restrict__ Wt2,
                         ushort* __restrict__ Wt3) {
    int i = blockIdx.x * 256 + threadIdx.x;
    if (i < 128 * 128) {
        int r = i >> 7, c = i & 127;
        Wt1[c * 128 + r] = bf16_bits(W1[i]);
        Wt2[c * 128 + r] = bf16_bits(W2[i]);
    }
    if (i < 128 * 64) {
        int r = i >> 6, c = i & 63;
        Wt3[c * 128 + r] = bf16_bits(W3[i]);
    }
}

// ---------------- MFMA GEMM: T = A @ W, bf16 in, bf16 out ----------------
// BM=64, 256 threads = 4 waves; wave w owns rows w*16..w*16+15, all OUT cols.
// A-frag: lane holds A[row=l&15][k=(l>>4)*8+i]; B-frag from Wt (= B^T) rows;
// D: col=l&15, row=(l>>4)*4+reg (m89/m91-verified layout).
template <int OUT, bool ABF16>
__global__ __launch_bounds__(256) void k_gemm_mfma(const void* __restrict__ Ain,
                                                   const ushort* __restrict__ Wt,
                                                   ushort* __restrict__ To, int n) {
    constexpr int NT = OUT / 16;
    __shared__ ushort As[64][136];
    __shared__ ushort Ws[OUT][136];
    const int tid = threadIdx.x;
    const int wave = tid >> 6, lane = tid & 63;
    const int m0 = blockIdx.x * 64;

#pragma unroll
    for (int it = 0; it < OUT / 16; ++it) {      // OUT*16 u16x8 chunks / 256
        int idx = it * 256 + tid;
        int r = idx >> 4;
        int c8 = (idx & 15) << 3;
        *(u16x8*)&Ws[r][c8] = *(const u16x8*)(Wt + r * 128 + c8);
    }
    if constexpr (ABF16) {
        const ushort* A = (const ushort*)Ain;
#pragma unroll
        for (int it = 0; it < 4; ++it) {
            int idx = it * 256 + tid;
            int r = idx >> 4;
            int c8 = (idx & 15) << 3;
            u16x8 v = {0, 0, 0, 0, 0, 0, 0, 0};
            if (m0 + r < n) v = *(const u16x8*)(A + (size_t)(m0 + r) * 128 + c8);
            *(u16x8*)&As[r][c8] = v;
        }
    } else {
        const float* A = (const float*)Ain;
#pragma unroll
        for (int it = 0; it < 8; ++it) {
            int idx = it * 256 + tid;
            int r = idx >> 5;
            int c4 = (idx & 31) << 2;
            float4 v = make_float4(0.f, 0.f, 0.f, 0.f);
            if (m0 + r < n) v = *(const float4*)(A + (size_t)(m0 + r) * 128 + c4);
            As[r][c4 + 0] = bf16_bits(v.x);
            As[r][c4 + 1] = bf16_bits(v.y);
            As[r][c4 + 2] = bf16_bits(v.z);
            As[r][c4 + 3] = bf16_bits(v.w);
        }
    }
    __syncthreads();

    const int lrow = lane & 15;
    const int kgrp = lane >> 4;

    s16x8 a[4];
#pragma unroll
    for (int kk = 0; kk < 4; ++kk)
        a[kk] = *(const s16x8*)&As[wave * 16 + lrow][kk * 32 + kgrp * 8];

    f32x4 acc[NT];
#pragma unroll
    for (int nt = 0; nt < NT; ++nt) {
        f32x4 c = {0.f, 0.f, 0.f, 0.f};
#pragma unroll
        for (int kk = 0; kk < 4; ++kk) {
            s16x8 b = *(const s16x8*)&Ws[nt * 16 + lrow][kk * 32 + kgrp * 8];
            c = __builtin_amdgcn_mfma_f32_16x16x32_bf16(a[kk], b, c, 0, 0, 0);
        }
        acc[nt] = c;
    }

#pragma unroll
    for (int j = 0; j < 4; ++j) {
        int row = m0 + wave * 16 + kgrp * 4 + j;
        if (row < n) {
#pragma unroll
            for (int nt = 0; nt < NT; ++nt)
                To[(size_t)row * OUT + nt * 16 + lrow] = bf16_bits(acc[nt][j]);
        }
    }
}

// ---------------- Aggregation: 2 nodes per wave, 16 gathers in flight -----
// Simple 1-deep metadata prefetch; exhausted node degrades to row-0 /
// weight-0 gathers (branch-free). D=128: lane owns dims {2*lane, 2*lane+1}
// -> one 4B gather per edge covers the 256B row per wave.
template <bool RELU>
__global__ __launch_bounds__(256) void k_agg128(const ushort* __restrict__ T,
                                                const int* __restrict__ offs,
                                                const uint* __restrict__ ep,
                                                const float* __restrict__ bias,
                                                uint* __restrict__ outq, int n) {
    int pr = blockIdx.x * 4 + (threadIdx.x >> 6);
    int lane = threadIdx.x & 63;
    int w0 = pr * 2;
    if (w0 >= n) return;
    int w1 = w0 + 1;
    bool has1 = (w1 < n);
    int eA = offs[w0], endA = offs[w0 + 1];
    int eB = has1 ? offs[w1] : 0;
    int endB = has1 ? offs[w1 + 1] : 0;

    const uint* Tl = (const uint*)T + lane;
    const uint4 z4 = make_uint4(0u, 0u, 0u, 0u);
    float a0 = 0.f, a1 = 0.f, c0 = 0.f, c1 = 0.f;

    uint4 mA0 = *(const uint4*)(ep + eA);
    uint4 mA1 = *(const uint4*)(ep + eA + 4);
    uint4 mB0 = z4, mB1 = z4;
    if (eB < endB) { mB0 = *(const uint4*)(ep + eB); mB1 = *(const uint4*)(ep + eB + 4); }

    for (;;) {
        uint rA0 = Tl[(size_t)(mA0.x & 0xffffu) * 64];
        uint rA1 = Tl[(size_t)(mA0.y & 0xffffu) * 64];
        uint rA2 = Tl[(size_t)(mA0.z & 0xffffu) * 64];
        uint rA3 = Tl[(size_t)(mA0.w & 0xffffu) * 64];
        uint rA4 = Tl[(size_t)(mA1.x & 0xffffu) * 64];
        uint rA5 = Tl[(size_t)(mA1.y & 0xffffu) * 64];
        uint rA6 = Tl[(size_t)(mA1.z & 0xffffu) * 64];
        uint rA7 = Tl[(size_t)(mA1.w & 0xffffu) * 64];
        uint rB0 = Tl[(size_t)(mB0.x & 0xffffu) * 64];
        uint rB1 = Tl[(size_t)(mB0.y & 0xffffu) * 64];
        uint rB2 = Tl[(size_t)(mB0.z & 0xffffu) * 64];
        uint rB3 = Tl[(size_t)(mB0.w & 0xffffu) * 64];
        uint rB4 = Tl[(size_t)(mB1.x & 0xffffu) * 64];
        uint rB5 = Tl[(size_t)(mB1.y & 0xffffu) * 64];
        uint rB6 = Tl[(size_t)(mB1.z & 0xffffu) * 64];
        uint rB7 = Tl[(size_t)(mB1.w & 0xffffu) * 64];
        float wA0 = dec_norm(mA0.x), wA1 = dec_norm(mA0.y);
        float wA2 = dec_norm(mA0.z), wA3 = dec_norm(mA0.w);
        float wA4 = dec_norm(mA1.x), wA5 = dec_norm(mA1.y);
        float wA6 = dec_norm(mA1.z), wA7 = dec_norm(mA1.w);
        float wB0 = dec_norm(mB0.x), wB1 = dec_norm(mB0.y);
        float wB2 = dec_norm(mB0.z), wB3 = dec_norm(mB0.w);
        float wB4 = dec_norm(mB1.x), wB5 = dec_norm(mB1.y);
        float wB6 = dec_norm(mB1.z), wB7 = dec_norm(mB1.w);
        eA += 8;
        eB += 8;
        bool moreA = (eA < endA), moreB = (eB < endB);
        if (moreA) { mA0 = *(const uint4*)(ep + eA); mA1 = *(const uint4*)(ep + eA + 4); }
        else       { mA0 = z4; mA1 = z4; }
        if (moreB) { mB0 = *(const uint4*)(ep + eB); mB1 = *(const uint4*)(ep + eB + 4); }
        else       { mB0 = z4; mB1 = z4; }
        a0 += wA0 * bfu_lo(rA0); a1 += wA0 * bfu_hi(rA0);
        a0 += wA1 * bfu_lo(rA1); a1 += wA1 * bfu_hi(rA1);
        a0 += wA2 * bfu_lo(rA2); a1 += wA2 * bfu_hi(rA2);
        a0 += wA3 * bfu_lo(rA3); a1 += wA3 * bfu_hi(rA3);
        a0 += wA4 * bfu_lo(rA4); a1 += wA4 * bfu_hi(rA4);
        a0 += wA5 * bfu_lo(rA5); a1 += wA5 * bfu_hi(rA5);
        a0 += wA6 * bfu_lo(rA6); a1 += wA6 * bfu_hi(rA6);
        a0 += wA7 * bfu_lo(rA7); a1 += wA7 * bfu_hi(rA7);
        c0 += wB0 * bfu_lo(rB0); c1 += wB0 * bfu_hi(rB0);
        c0 += wB1 * bfu_lo(rB1); c1 += wB1 * bfu_hi(rB1);
        c0 += wB2 * bfu_lo(rB2); c1 += wB2 * bfu_hi(rB2);
        c0 += wB3 * bfu_lo(rB3); c1 += wB3 * bfu_hi(rB3);
        c0 += wB4 * bfu_lo(rB4); c1 += wB4 * bfu_hi(rB4);
        c0 += wB5 * bfu_lo(rB5); c1 += wB5 * bfu_hi(rB5);
        c0 += wB6 * bfu_lo(rB6); c1 += wB6 * bfu_hi(rB6);
        c0 += wB7 * bfu_lo(rB7); c1 += wB7 * bfu_hi(rB7);
        if (!moreA && !moreB) break;
    }

    float2 b = *(const float2*)(bias + (lane << 1));
    a0 += b.x; a1 += b.y;
    if (RELU) { a0 = fmaxf(a0, 0.f); a1 = fmaxf(a1, 0.f); }
    outq[(size_t)w0 * 64 + lane] = ((uint)bf16_bits(a1) << 16) | (uint)bf16_bits(a0);
    if (has1) {
        c0 += b.x; c1 += b.y;
        if (RELU) { c0 = fmaxf(c0, 0.f); c1 = fmaxf(c1, 0.f); }
        outq[(size_t)w1 * 64 + lane] = ((uint)bf16_bits(c1) << 16) | (uint)bf16_bits(c0);
    }
}

// D=64 final layer: lane owns 1 dim, fp32 output, 2 nodes per wave.
__global__ __launch_bounds__(256) void k_agg64(const ushort* __restrict__ T,
                                               const int* __restrict__ offs,
                                               const uint* __restrict__ ep,
                                               const float* __restrict__ bias,
                                               float* __restrict__ out, int n) {
    int pr = blockIdx.x * 4 + (threadIdx.x >> 6);
    int lane = threadIdx.x & 63;
    int w0 = pr * 2;
    if (w0 >= n) return;
    int w1 = w0 + 1;
    bool has1 = (w1 < n);
    int eA = offs[w0], endA = offs[w0 + 1];
    int eB = has1 ? offs[w1] : 0;
    int endB = has1 ? offs[w1 + 1] : 0;

    const ushort* Tl = T + lane;
    const uint4 z4 = make_uint4(0u, 0u, 0u, 0u);
    float a0 = 0.f, c0 = 0.f;

    uint4 mA0 = *(const uint4*)(ep + eA);
    uint4 mA1 = *(const uint4*)(ep + eA + 4);
    uint4 mB0 = z4, mB1 = z4;
    if (eB < endB) { mB0 = *(const uint4*)(ep + eB); mB1 = *(const uint4*)(ep + eB + 4); }

    for (;;) {
        float rA0 = __uint_as_float((uint)Tl[(size_t)(mA0.x & 0xffffu) * 64] << 16);
        float rA1 = __uint_as_float((uint)Tl[(size_t)(mA0.y & 0xffffu) * 64] << 16);
        float rA2 = __uint_as_float((uint)Tl[(size_t)(mA0.z & 0xffffu) * 64] << 16);
        float rA3 = __uint_as_float((uint)Tl[(size_t)(mA0.w & 0xffffu) * 64] << 16);
        float rA4 = __uint_as_float((uint)Tl[(size_t)(mA1.x & 0xffffu) * 64] << 16);
        float rA5 = __uint_as_float((uint)Tl[(size_t)(mA1.y & 0xffffu) * 64] << 16);
        float rA6 = __uint_as_float((uint)Tl[(size_t)(mA1.z & 0xffffu) * 64] << 16);
        float rA7 = __uint_as_float((uint)Tl[(size_t)(mA1.w & 0xffffu) * 64] << 16);
        float rB0 = __uint_as_float((uint)Tl[(size_t)(mB0.x & 0xffffu) * 64] << 16);
        float rB1 = __uint_as_float((uint)Tl[(size_t)(mB0.y & 0xffffu) * 64] << 16);
        float rB2 = __uint_as_float((uint)Tl[(size_t)(mB0.z & 0xffffu) * 64] << 16);
        float rB3 = __uint_as_float((uint)Tl[(size_t)(mB0.w & 0xffffu) * 64] << 16);
        float rB4 = __uint_as_float((uint)Tl[(size_t)(mB1.x & 0xffffu) * 64] << 16);
        float rB5 = __uint_as_float((uint)Tl[(size_t)(mB1.y & 0xffffu) * 64] << 16);
        float rB6 = __uint_as_float((uint)Tl[(size_t)(mB1.z & 0xffffu) * 64] << 16);
        float rB7 = __uint_as_float((uint)Tl[(size_t)(mB1.w & 0xffffu) * 64] << 16);
        float wA0 = dec_norm(mA0.x), wA1 = dec_norm(mA0.y);
        float wA2 = dec_norm(mA0.z), wA3 = dec_norm(mA0.w);
        float wA4 = dec_norm(mA1.x), wA5 = dec_norm(mA1.y);
        float wA6 = dec_norm(mA1.z), wA7 = dec_norm(mA1.w);
        float wB0 = dec_norm(mB0.x), wB1 = dec_norm(mB0.y);
        float wB2 = dec_norm(mB0.z), wB3 = dec_norm(mB0.w);
        float wB4 = dec_norm(mB1.x), wB5 = dec_norm(mB1.y);
        float wB6 = dec_norm(mB1.z), wB7 = dec_norm(mB1.w);
        eA += 8;
        eB += 8;
        bool moreA = (eA < endA), moreB = (eB < endB);
        if (moreA) { mA0 = *(const uint4*)(ep + eA); mA1 = *(const uint4*)(ep + eA + 4); }
        else       { mA0 = z4; mA1 = z4; }
        if (moreB) { mB0 = *(const uint4*)(ep + eB); mB1 = *(const uint4*)(ep + eB + 4); }
        else       { mB0 = z4; mB1 = z4; }
        a0 += wA0 * rA0 + wA1 * rA1 + wA2 * rA2 + wA3 * rA3;
        a0 += wA4 * rA4 + wA5 * rA5 + wA6 * rA6 + wA7 * rA7;
        c0 += wB0 * rB0 + wB1 * rB1 + wB2 * rB2 + wB3 * rB3;
        c0 += wB4 * rB4 + wB5 * rB5 + wB6 * rB6 + wB7 * rB7;
        if (!moreA && !moreB) break;
    }

    float bv = bias[lane];
    out[(size_t)w0 * 64 + lane] = a0 + bv;
    if (has1) out[(size_t)w1 * 64 + lane] = c0 + bv;
}

// ---------------------------------------------------------------------------

extern "C" void kernel_launch(void* const* d_in, const int* in_sizes, int n_in,
                              void* d_out, int out_size, void* d_ws, size_t ws_size,
                              hipStream_t stream) {
    const int n = in_sizes[0] / 128;   // 50000
    const int E = in_sizes[1] / 2;     // 800000

    const float* x  = (const float*)d_in[0];
    const int*   ei = (const int*)d_in[1];
    const float* W1 = (const float*)d_in[2];
    const float* b1 = (const float*)d_in[3];
    const float* W2 = (const float*)d_in[4];
    const float* b2 = (const float*)d_in[5];
    const float* W3 = (const float*)d_in[6];
    const float* b3 = (const float*)d_in[7];
    const int* src = ei;
    const int* dst = ei + E;
    float* out = (float*)d_out;

    const int cap = E + 8 * n;  // max padded slots

    char* w = (char*)d_ws;
    auto alloc = [&](size_t bytes) {
        char* p = w;
        w += (bytes + 255) & ~(size_t)255;
        return p;
    };
    int*    deg    = (int*)alloc((size_t)n * 4);
    int*    offs   = (int*)alloc((size_t)(n + 1) * 4);
    int*    bsum   = (int*)alloc(256 * 4);
    float*  dinv   = (float*)alloc((size_t)n * 4);
    ushort* rank   = (ushort*)alloc((size_t)E * 2);
    uint*   ep     = (uint*)alloc((size_t)cap * 4);
    ushort* tA     = (ushort*)alloc((size_t)n * 128 * 2);  // gathered t (bf16)
    uint*   hB     = (uint*)alloc((size_t)n * 64 * 4);     // h packed bf16x2
    ushort* Wt1    = (ushort*)alloc(128 * 128 * 2);
    ushort* Wt2    = (ushort*)alloc(128 * 128 * 2);
    ushort* Wt3    = (ushort*)alloc(64 * 128 * 2);

    const int nb = (n + 255) / 256;

    // ---- CSR build + weight prep ----
    const int cap4 = (cap + 3) / 4;
    k_init<<<(cap4 + 255) / 256, 256, 0, stream>>>(deg, n, (uint4*)ep, cap4);
    k_transW<<<64, 256, 0, stream>>>(W1, W2, W3, Wt1, Wt2, Wt3);
    k_hist<<<(E + 255) / 256, 256, 0, stream>>>(dst, E, deg, rank);
    k_scan_block<<<nb, 256, 0, stream>>>(deg, offs, bsum, dinv, n);
    k_scan_bsum<<<1, 256, 0, stream>>>(bsum, nb, offs, n);
    k_add_bsum<<<nb, 256, 0, stream>>>(offs, bsum, n);
    k_fill<<<(E + n + 255) / 256, 256, 0, stream>>>(src, dst, rank, E, n, offs, dinv, ep);

    // ---- 3 GCN layers ----
    const int pair_blocks = ((n + 1) / 2 + 3) / 4;   // 2 nodes/wave, 4 waves/block
    const int gemm_blocks = (n + 63) / 64;

    k_gemm_mfma<128, false><<<gemm_blocks, 256, 0, stream>>>(x, Wt1, tA, n);
    k_agg128<true><<<pair_blocks, 256, 0, stream>>>(tA, offs, ep, b1, hB, n);

    k_gemm_mfma<128, true><<<gemm_blocks, 256, 0, stream>>>(hB, Wt2, tA, n);
    k_agg128<true><<<pair_blocks, 256, 0, stream>>>(tA, offs, ep, b2, hB, n);

    k_gemm_mfma<64, true><<<gemm_blocks, 256, 0, stream>>>(hB, Wt3, tA, n);
    k_agg64<<<pair_blocks, 256, 0, stream>>>(tA, offs, ep, b3, out, n);
}

// Round 13
// 181.647 us; speedup vs baseline: 1.2089x; 1.0327x over previous
//
#include <hip/hip_runtime.h>
#include <hip/hip_bf16.h>
#include <hip/hip_fp16.h>

// ---------------------------------------------------------------------------
// GCN 3-layer forward.
//  - All 3 GEMMs: bf16 MFMA (16x16x32), fp32 accum, bf16 output.
//  - agg128: CSR gather of bf16 rows, fp32 accum, 2 nodes/wave, 16 gathers in
//    flight, 1-deep metadata prefetch (R9 structure; deeper pipelines regressed).
//  - agg64: 4 nodes/wave, 32-lane rows (uint loads = 2 dims/lane) — full-width
//    loads, half the waves of the 2-node ushort version.
//  - CSR build via RANK-FROM-HIST (atomic's return value = slot rank); fill is
//    atomic-free and edge-only (self-loops written by k_add_bsum); hist/fill
//    vectorized 2 edges/thread; init+transW fused.
//  - Edge record: u32 {fp16 norm | u16 src}. Rows padded to x8, pad = 0.
//    Self-loop occupies reserved rank 0 (deg initialized to 1).
// ---------------------------------------------------------------------------

typedef __attribute__((ext_vector_type(8))) short s16x8;
typedef __attribute__((ext_vector_type(8))) unsigned short u16x8;
typedef __attribute__((ext_vector_type(4))) float f32x4;

__device__ __forceinline__ float bfu_lo(uint v) { return __uint_as_float(v << 16); }
__device__ __forceinline__ float bfu_hi(uint v) { return __uint_as_float(v & 0xffff0000u); }
__device__ __forceinline__ float dec_norm(uint m) {
    return __half2float(__ushort_as_half((ushort)(m >> 16)));
}
__device__ __forceinline__ ushort bf16_bits(float f) {
    union { __hip_bfloat16 h; ushort u; } x;
    x.h = __float2bfloat16(f);
    return x.u;
}

// ---------------- init + weight transpose/quantize (fused) ----------------
__global__ void k_init(const float* __restrict__ W1, const float* __restrict__ W2,
                       const float* __restrict__ W3,
                       ushort* __restrict__ Wt1, ushort* __restrict__ Wt2,
                       ushort* __restrict__ Wt3,
                       int* __restrict__ deg, int n,
                       uint4* __restrict__ ep4, int cap4) {
    int i = blockIdx.x * blockDim.x + threadIdx.x;
    if (i < n) deg[i] = 1;                       // slot 0 reserved: self-loop
    if (i < cap4) ep4[i] = make_uint4(0u, 0u, 0u, 0u);
    if (i < 128 * 128) {
        int r = i >> 7, c = i & 127;
        Wt1[c * 128 + r] = bf16_bits(W1[i]);
        Wt2[c * 128 + r] = bf16_bits(W2[i]);
    }
    if (i < 128 * 64) {
        int r = i >> 6, c = i & 63;
        Wt3[c * 128 + r] = bf16_bits(W3[i]);
    }
}

// histogram + per-edge rank (atomic's return value IS the CSR slot rank).
// 2 edges per thread (int2 load, ushort2 store).
__global__ void k_hist(const int* __restrict__ dst, int E,
                       int* __restrict__ deg, ushort* __restrict__ rank) {
    int e2 = (blockIdx.x * blockDim.x + threadIdx.x) * 2;
    if (e2 >= E) return;
    int2 d2 = *(const int2*)(dst + e2);
    int r0 = atomicAdd(&deg[d2.x], 1);
    if (e2 + 1 < E) {
        int r1 = atomicAdd(&deg[d2.y], 1);
        *(ushort2*)(rank + e2) = make_ushort2((ushort)r0, (ushort)r1);
    } else {
        rank[e2] = (ushort)r0;
    }
}

__global__ void k_scan_block(const int* __restrict__ deg, int* __restrict__ offs,
                             int* __restrict__ bsum, float* __restrict__ dinv, int n) {
    __shared__ int sm[256];
    int tid = threadIdx.x;
    int i = blockIdx.x * 256 + tid;
    int v = (i < n) ? deg[i] : 0;
    int pv = (i < n) ? ((v + 7) & ~7) : 0;   // pad rows to x8
    if (i < n) dinv[i] = rsqrtf((float)v);
    sm[tid] = pv;
    __syncthreads();
    for (int off = 1; off < 256; off <<= 1) {
        int t = (tid >= off) ? sm[tid - off] : 0;
        __syncthreads();
        sm[tid] += t;
        __syncthreads();
    }
    if (i < n) offs[i] = sm[tid] - pv;
    if (tid == 255) bsum[blockIdx.x] = sm[255];
}

__global__ void k_scan_bsum(int* __restrict__ bsum, int nb, int* __restrict__ offs, int n) {
    __shared__ int sm[256];
    int tid = threadIdx.x;
    int v = (tid < nb) ? bsum[tid] : 0;
    sm[tid] = v;
    __syncthreads();
    for (int off = 1; off < 256; off <<= 1) {
        int t = (tid >= off) ? sm[tid - off] : 0;
        __syncthreads();
        sm[tid] += t;
        __syncthreads();
    }
    if (tid < nb) bsum[tid] = sm[tid] - v;
    if (tid == 255) offs[n] = sm[255];
}

// finalize offs AND write the self-loop record (rank 0) for each node.
__global__ void k_add_bsum(int* __restrict__ offs, const int* __restrict__ bsum,
                           const float* __restrict__ dinv, uint* __restrict__ ep, int n) {
    int i = blockIdx.x * blockDim.x + threadIdx.x;
    if (i < n) {
        int o = offs[i] + bsum[i >> 8];
        offs[i] = o;
        float dv = dinv[i];
        uint hb = (uint)__half_as_ushort(__float2half(dv * dv));
        ep[o] = (hb << 16) | (uint)i;            // self-loop at rank 0
    }
}

// atomic-free CSR fill, edges only, 2 per thread: pos = offs[dst] + rank.
__global__ __launch_bounds__(256) void k_fill(const int* __restrict__ src,
                                              const int* __restrict__ dst,
                                              const ushort* __restrict__ rank,
                                              int E,
                                              const int* __restrict__ offs,
                                              const float* __restrict__ dinv,
                                              uint* __restrict__ ep) {
    int e2 = (blockIdx.x * blockDim.x + threadIdx.x) * 2;
    if (e2 >= E) return;
    int2 s2 = *(const int2*)(src + e2);
    int2 d2 = *(const int2*)(dst + e2);
    ushort2 r2 = *(const ushort2*)(rank + e2);
    {
        int pos = offs[d2.x] + (int)r2.x;
        uint hb = (uint)__half_as_ushort(__float2half(dinv[s2.x] * dinv[d2.x]));
        ep[pos] = (hb << 16) | (uint)s2.x;
    }
    if (e2 + 1 < E) {
        int pos = offs[d2.y] + (int)r2.y;
        uint hb = (uint)__half_as_ushort(__float2half(dinv[s2.y] * dinv[d2.y]));
        ep[pos] = (hb << 16) | (uint)s2.y;
    }
}

// ---------------- MFMA GEMM: T = A @ W, bf16 in, bf16 out ----------------
// BM=64, 256 threads = 4 waves; wave w owns rows w*16..w*16+15, all OUT cols.
template <int OUT, bool ABF16>
__global__ __launch_bounds__(256) void k_gemm_mfma(const void* __restrict__ Ain,
                                                   const ushort* __restrict__ Wt,
                                                   ushort* __restrict__ To, int n) {
    constexpr int NT = OUT / 16;
    __shared__ ushort As[64][136];
    __shared__ ushort Ws[OUT][136];
    const int tid = threadIdx.x;
    const int wave = tid >> 6, lane = tid & 63;
    const int m0 = blockIdx.x * 64;

#pragma unroll
    for (int it = 0; it < OUT / 16; ++it) {
        int idx = it * 256 + tid;
        int r = idx >> 4;
        int c8 = (idx & 15) << 3;
        *(u16x8*)&Ws[r][c8] = *(const u16x8*)(Wt + r * 128 + c8);
    }
    if constexpr (ABF16) {
        const ushort* A = (const ushort*)Ain;
#pragma unroll
        for (int it = 0; it < 4; ++it) {
            int idx = it * 256 + tid;
            int r = idx >> 4;
            int c8 = (idx & 15) << 3;
            u16x8 v = {0, 0, 0, 0, 0, 0, 0, 0};
            if (m0 + r < n) v = *(const u16x8*)(A + (size_t)(m0 + r) * 128 + c8);
            *(u16x8*)&As[r][c8] = v;
        }
    } else {
        const float* A = (const float*)Ain;
#pragma unroll
        for (int it = 0; it < 8; ++it) {
            int idx = it * 256 + tid;
            int r = idx >> 5;
            int c4 = (idx & 31) << 2;
            float4 v = make_float4(0.f, 0.f, 0.f, 0.f);
            if (m0 + r < n) v = *(const float4*)(A + (size_t)(m0 + r) * 128 + c4);
            As[r][c4 + 0] = bf16_bits(v.x);
            As[r][c4 + 1] = bf16_bits(v.y);
            As[r][c4 + 2] = bf16_bits(v.z);
            As[r][c4 + 3] = bf16_bits(v.w);
        }
    }
    __syncthreads();

    const int lrow = lane & 15;
    const int kgrp = lane >> 4;

    s16x8 a[4];
#pragma unroll
    for (int kk = 0; kk < 4; ++kk)
        a[kk] = *(const s16x8*)&As[wave * 16 + lrow][kk * 32 + kgrp * 8];

    f32x4 acc[NT];
#pragma unroll
    for (int nt = 0; nt < NT; ++nt) {
        f32x4 c = {0.f, 0.f, 0.f, 0.f};
#pragma unroll
        for (int kk = 0; kk < 4; ++kk) {
            s16x8 b = *(const s16x8*)&Ws[nt * 16 + lrow][kk * 32 + kgrp * 8];
            c = __builtin_amdgcn_mfma_f32_16x16x32_bf16(a[kk], b, c, 0, 0, 0);
        }
        acc[nt] = c;
    }

#pragma unroll
    for (int j = 0; j < 4; ++j) {
        int row = m0 + wave * 16 + kgrp * 4 + j;
        if (row < n) {
#pragma unroll
            for (int nt = 0; nt < NT; ++nt)
                To[(size_t)row * OUT + nt * 16 + lrow] = bf16_bits(acc[nt][j]);
        }
    }
}

// ---------------- agg128: 2 nodes per wave, 16 gathers in flight ----------
// D=128: lane owns dims {2*lane, 2*lane+1} -> one 4B gather per edge covers
// the 256B row per wave. 1-deep metadata prefetch; exhausted node degrades
// to row-0 / weight-0 gathers (branch-free).
template <bool RELU>
__global__ __launch_bounds__(256) void k_agg128(const ushort* __restrict__ T,
                                                const int* __restrict__ offs,
                                                const uint* __restrict__ ep,
                                                const float* __restrict__ bias,
                                                uint* __restrict__ outq, int n) {
    int pr = blockIdx.x * 4 + (threadIdx.x >> 6);
    int lane = threadIdx.x & 63;
    int w0 = pr * 2;
    if (w0 >= n) return;
    int w1 = w0 + 1;
    bool has1 = (w1 < n);
    int eA = offs[w0], endA = offs[w0 + 1];
    int eB = has1 ? offs[w1] : 0;
    int endB = has1 ? offs[w1 + 1] : 0;

    const uint* Tl = (const uint*)T + lane;
    const uint4 z4 = make_uint4(0u, 0u, 0u, 0u);
    float a0 = 0.f, a1 = 0.f, c0 = 0.f, c1 = 0.f;

    uint4 mA0 = *(const uint4*)(ep + eA);
    uint4 mA1 = *(const uint4*)(ep + eA + 4);
    uint4 mB0 = z4, mB1 = z4;
    if (eB < endB) { mB0 = *(const uint4*)(ep + eB); mB1 = *(const uint4*)(ep + eB + 4); }

    for (;;) {
        uint rA0 = Tl[(size_t)(mA0.x & 0xffffu) * 64];
        uint rA1 = Tl[(size_t)(mA0.y & 0xffffu) * 64];
        uint rA2 = Tl[(size_t)(mA0.z & 0xffffu) * 64];
        uint rA3 = Tl[(size_t)(mA0.w & 0xffffu) * 64];
        uint rA4 = Tl[(size_t)(mA1.x & 0xffffu) * 64];
        uint rA5 = Tl[(size_t)(mA1.y & 0xffffu) * 64];
        uint rA6 = Tl[(size_t)(mA1.z & 0xffffu) * 64];
        uint rA7 = Tl[(size_t)(mA1.w & 0xffffu) * 64];
        uint rB0 = Tl[(size_t)(mB0.x & 0xffffu) * 64];
        uint rB1 = Tl[(size_t)(mB0.y & 0xffffu) * 64];
        uint rB2 = Tl[(size_t)(mB0.z & 0xffffu) * 64];
        uint rB3 = Tl[(size_t)(mB0.w & 0xffffu) * 64];
        uint rB4 = Tl[(size_t)(mB1.x & 0xffffu) * 64];
        uint rB5 = Tl[(size_t)(mB1.y & 0xffffu) * 64];
        uint rB6 = Tl[(size_t)(mB1.z & 0xffffu) * 64];
        uint rB7 = Tl[(size_t)(mB1.w & 0xffffu) * 64];
        float wA0 = dec_norm(mA0.x), wA1 = dec_norm(mA0.y);
        float wA2 = dec_norm(mA0.z), wA3 = dec_norm(mA0.w);
        float wA4 = dec_norm(mA1.x), wA5 = dec_norm(mA1.y);
        float wA6 = dec_norm(mA1.z), wA7 = dec_norm(mA1.w);
        float wB0 = dec_norm(mB0.x), wB1 = dec_norm(mB0.y);
        float wB2 = dec_norm(mB0.z), wB3 = dec_norm(mB0.w);
        float wB4 = dec_norm(mB1.x), wB5 = dec_norm(mB1.y);
        float wB6 = dec_norm(mB1.z), wB7 = dec_norm(mB1.w);
        eA += 8;
        eB += 8;
        bool moreA = (eA < endA), moreB = (eB < endB);
        if (moreA) { mA0 = *(const uint4*)(ep + eA); mA1 = *(const uint4*)(ep + eA + 4); }
        else       { mA0 = z4; mA1 = z4; }
        if (moreB) { mB0 = *(const uint4*)(ep + eB); mB1 = *(const uint4*)(ep + eB + 4); }
        else       { mB0 = z4; mB1 = z4; }
        a0 += wA0 * bfu_lo(rA0); a1 += wA0 * bfu_hi(rA0);
        a0 += wA1 * bfu_lo(rA1); a1 += wA1 * bfu_hi(rA1);
        a0 += wA2 * bfu_lo(rA2); a1 += wA2 * bfu_hi(rA2);
        a0 += wA3 * bfu_lo(rA3); a1 += wA3 * bfu_hi(rA3);
        a0 += wA4 * bfu_lo(rA4); a1 += wA4 * bfu_hi(rA4);
        a0 += wA5 * bfu_lo(rA5); a1 += wA5 * bfu_hi(rA5);
        a0 += wA6 * bfu_lo(rA6); a1 += wA6 * bfu_hi(rA6);
        a0 += wA7 * bfu_lo(rA7); a1 += wA7 * bfu_hi(rA7);
        c0 += wB0 * bfu_lo(rB0); c1 += wB0 * bfu_hi(rB0);
        c0 += wB1 * bfu_lo(rB1); c1 += wB1 * bfu_hi(rB1);
        c0 += wB2 * bfu_lo(rB2); c1 += wB2 * bfu_hi(rB2);
        c0 += wB3 * bfu_lo(rB3); c1 += wB3 * bfu_hi(rB3);
        c0 += wB4 * bfu_lo(rB4); c1 += wB4 * bfu_hi(rB4);
        c0 += wB5 * bfu_lo(rB5); c1 += wB5 * bfu_hi(rB5);
        c0 += wB6 * bfu_lo(rB6); c1 += wB6 * bfu_hi(rB6);
        c0 += wB7 * bfu_lo(rB7); c1 += wB7 * bfu_hi(rB7);
        if (!moreA && !moreB) break;
    }

    float2 b = *(const float2*)(bias + (lane << 1));
    a0 += b.x; a1 += b.y;
    if (RELU) { a0 = fmaxf(a0, 0.f); a1 = fmaxf(a1, 0.f); }
    outq[(size_t)w0 * 64 + lane] = ((uint)bf16_bits(a1) << 16) | (uint)bf16_bits(a0);
    if (has1) {
        c0 += b.x; c1 += b.y;
        if (RELU) { c0 = fmaxf(c0, 0.f); c1 = fmaxf(c1, 0.f); }
        outq[(size_t)w1 * 64 + lane] = ((uint)bf16_bits(c1) << 16) | (uint)bf16_bits(c0);
    }
}

// ---------------- agg64: 4 nodes per wave, 32-lane rows -------------------
// Lane loads a uint (2 dims); 32 lanes cover a 64-dim bf16 row. Wave halves
// each run an independent 2-node stream pair (divergent exit is per-half;
// exec mask handles it). fp32 output.
__global__ __launch_bounds__(256) void k_agg64(const ushort* __restrict__ T,
                                               const int* __restrict__ offs,
                                               const uint* __restrict__ ep,
                                               const float* __restrict__ bias,
                                               float* __restrict__ out, int n) {
    int wv = blockIdx.x * 4 + (threadIdx.x >> 6);
    int lane = threadIdx.x & 63;
    int half = lane >> 5;
    int lh = lane & 31;
    int base = wv * 4;
    if (base >= n) return;
    int wA = base + half * 2;
    int wB = wA + 1;
    int eA = 0, endA = 0, eB = 0, endB = 0;
    if (wA < n) { eA = offs[wA]; endA = offs[wA + 1]; }
    if (wB < n) { eB = offs[wB]; endB = offs[wB + 1]; }

    const uint* Tl = (const uint*)T + lh;    // row = 32 uints (64 bf16 dims)
    const uint4 z4 = make_uint4(0u, 0u, 0u, 0u);
    float a0 = 0.f, a1 = 0.f, c0 = 0.f, c1 = 0.f;

    uint4 mA0 = z4, mA1 = z4, mB0 = z4, mB1 = z4;
    if (eA < endA) { mA0 = *(const uint4*)(ep + eA); mA1 = *(const uint4*)(ep + eA + 4); }
    if (eB < endB) { mB0 = *(const uint4*)(ep + eB); mB1 = *(const uint4*)(ep + eB + 4); }

    for (;;) {
        uint rA0 = Tl[(size_t)(mA0.x & 0xffffu) * 32];
        uint rA1 = Tl[(size_t)(mA0.y & 0xffffu) * 32];
        uint rA2 = Tl[(size_t)(mA0.z & 0xffffu) * 32];
        uint rA3 = Tl[(size_t)(mA0.w & 0xffffu) * 32];
        uint rA4 = Tl[(size_t)(mA1.x & 0xffffu) * 32];
        uint rA5 = Tl[(size_t)(mA1.y & 0xffffu) * 32];
        uint rA6 = Tl[(size_t)(mA1.z & 0xffffu) * 32];
        uint rA7 = Tl[(size_t)(mA1.w & 0xffffu) * 32];
        uint rB0 = Tl[(size_t)(mB0.x & 0xffffu) * 32];
        uint rB1 = Tl[(size_t)(mB0.y & 0xffffu) * 32];
        uint rB2 = Tl[(size_t)(mB0.z & 0xffffu) * 32];
        uint rB3 = Tl[(size_t)(mB0.w & 0xffffu) * 32];
        uint rB4 = Tl[(size_t)(mB1.x & 0xffffu) * 32];
        uint rB5 = Tl[(size_t)(mB1.y & 0xffffu) * 32];
        uint rB6 = Tl[(size_t)(mB1.z & 0xffffu) * 32];
        uint rB7 = Tl[(size_t)(mB1.w & 0xffffu) * 32];
        float wA0 = dec_norm(mA0.x), wA1 = dec_norm(mA0.y);
        float wA2 = dec_norm(mA0.z), wA3 = dec_norm(mA0.w);
        float wA4 = dec_norm(mA1.x), wA5 = dec_norm(mA1.y);
        float wA6 = dec_norm(mA1.z), wA7 = dec_norm(mA1.w);
        float wB0 = dec_norm(mB0.x), wB1 = dec_norm(mB0.y);
        float wB2 = dec_norm(mB0.z), wB3 = dec_norm(mB0.w);
        float wB4 = dec_norm(mB1.x), wB5 = dec_norm(mB1.y);
        float wB6 = dec_norm(mB1.z), wB7 = dec_norm(mB1.w);
        eA += 8;
        eB += 8;
        bool moreA = (eA < endA), moreB = (eB < endB);
        if (moreA) { mA0 = *(const uint4*)(ep + eA); mA1 = *(const uint4*)(ep + eA + 4); }
        else       { mA0 = z4; mA1 = z4; }
        if (moreB) { mB0 = *(const uint4*)(ep + eB); mB1 = *(const uint4*)(ep + eB + 4); }
        else       { mB0 = z4; mB1 = z4; }
        a0 += wA0 * bfu_lo(rA0); a1 += wA0 * bfu_hi(rA0);
        a0 += wA1 * bfu_lo(rA1); a1 += wA1 * bfu_hi(rA1);
        a0 += wA2 * bfu_lo(rA2); a1 += wA2 * bfu_hi(rA2);
        a0 += wA3 * bfu_lo(rA3); a1 += wA3 * bfu_hi(rA3);
        a0 += wA4 * bfu_lo(rA4); a1 += wA4 * bfu_hi(rA4);
        a0 += wA5 * bfu_lo(rA5); a1 += wA5 * bfu_hi(rA5);
        a0 += wA6 * bfu_lo(rA6); a1 += wA6 * bfu_hi(rA6);
        a0 += wA7 * bfu_lo(rA7); a1 += wA7 * bfu_hi(rA7);
        c0 += wB0 * bfu_lo(rB0); c1 += wB0 * bfu_hi(rB0);
        c0 += wB1 * bfu_lo(rB1); c1 += wB1 * bfu_hi(rB1);
        c0 += wB2 * bfu_lo(rB2); c1 += wB2 * bfu_hi(rB2);
        c0 += wB3 * bfu_lo(rB3); c1 += wB3 * bfu_hi(rB3);
        c0 += wB4 * bfu_lo(rB4); c1 += wB4 * bfu_hi(rB4);
        c0 += wB5 * bfu_lo(rB5); c1 += wB5 * bfu_hi(rB5);
        c0 += wB6 * bfu_lo(rB6); c1 += wB6 * bfu_hi(rB6);
        c0 += wB7 * bfu_lo(rB7); c1 += wB7 * bfu_hi(rB7);
        if (!moreA && !moreB) break;
    }

    float2 b = *(const float2*)(bias + (lh << 1));
    if (wA < n)
        *(float2*)(out + (size_t)wA * 64 + (lh << 1)) = make_float2(a0 + b.x, a1 + b.y);
    if (wB < n)
        *(float2*)(out + (size_t)wB * 64 + (lh << 1)) = make_float2(c0 + b.x, c1 + b.y);
}

// ---------------------------------------------------------------------------

extern "C" void kernel_launch(void* const* d_in, const int* in_sizes, int n_in,
                              void* d_out, int out_size, void* d_ws, size_t ws_size,
                              hipStream_t stream) {
    const int n = in_sizes[0] / 128;   // 50000
    const int E = in_sizes[1] / 2;     // 800000

    const float* x  = (const float*)d_in[0];
    const int*   ei = (const int*)d_in[1];
    const float* W1 = (const float*)d_in[2];
    const float* b1 = (const float*)d_in[3];
    const float* W2 = (const float*)d_in[4];
    const float* b2 = (const float*)d_in[5];
    const float* W3 = (const float*)d_in[6];
    const float* b3 = (const float*)d_in[7];
    const int* src = ei;
    const int* dst = ei + E;
    float* out = (float*)d_out;

    const int cap = E + 8 * n;  // max padded slots

    char* w = (char*)d_ws;
    auto alloc = [&](size_t bytes) {
        char* p = w;
        w += (bytes + 255) & ~(size_t)255;
        return p;
    };
    int*    deg    = (int*)alloc((size_t)n * 4);
    int*    offs   = (int*)alloc((size_t)(n + 1) * 4);
    int*    bsum   = (int*)alloc(256 * 4);
    float*  dinv   = (float*)alloc((size_t)n * 4);
    ushort* rank   = (ushort*)alloc((size_t)E * 2);
    uint*   ep     = (uint*)alloc((size_t)cap * 4);
    ushort* tA     = (ushort*)alloc((size_t)n * 128 * 2);  // gathered t (bf16)
    uint*   hB     = (uint*)alloc((size_t)n * 64 * 4);     // h packed bf16x2
    ushort* Wt1    = (ushort*)alloc(128 * 128 * 2);
    ushort* Wt2    = (ushort*)alloc(128 * 128 * 2);
    ushort* Wt3    = (ushort*)alloc(64 * 128 * 2);

    const int nb = (n + 255) / 256;

    // ---- CSR build + weight prep ----
    const int cap4 = (cap + 3) / 4;
    const int init_n = max(cap4, n);
    k_init<<<(init_n + 255) / 256, 256, 0, stream>>>(W1, W2, W3, Wt1, Wt2, Wt3,
                                                     deg, n, (uint4*)ep, cap4);
    k_hist<<<(E / 2 + 255) / 256, 256, 0, stream>>>(dst, E, deg, rank);
    k_scan_block<<<nb, 256, 0, stream>>>(deg, offs, bsum, dinv, n);
    k_scan_bsum<<<1, 256, 0, stream>>>(bsum, nb, offs, n);
    k_add_bsum<<<nb, 256, 0, stream>>>(offs, bsum, dinv, ep, n);
    k_fill<<<(E / 2 + 255) / 256, 256, 0, stream>>>(src, dst, rank, E, offs, dinv, ep);

    // ---- 3 GCN layers ----
    const int pair_blocks = ((n + 1) / 2 + 3) / 4;   // agg128: 2 nodes/wave
    const int quad_blocks = ((n + 3) / 4 + 3) / 4;   // agg64: 4 nodes/wave
    const int gemm_blocks = (n + 63) / 64;

    k_gemm_mfma<128, false><<<gemm_blocks, 256, 0, stream>>>(x, Wt1, tA, n);
    k_agg128<true><<<pair_blocks, 256, 0, stream>>>(tA, offs, ep, b1, hB, n);

    k_gemm_mfma<128, true><<<gemm_blocks, 256, 0, stream>>>(hB, Wt2, tA, n);
    k_agg128<true><<<pair_blocks, 256, 0, stream>>>(tA, offs, ep, b2, hB, n);

    k_gemm_mfma<64, true><<<gemm_blocks, 256, 0, stream>>>(hB, Wt3, tA, n);
    k_agg64<<<quad_blocks, 256, 0, stream>>>(tA, offs, ep, b3, out, n);
}